// Round 2
// 75.715 us; speedup vs baseline: 1.0212x; 1.0212x over previous
//
#include <hip/hip_runtime.h>
#include <hip/hip_fp16.h>
#include <math.h>

#define NG 512
#define WI 256
#define HI 256
#define FXc 256.0f   // W / (2*tanfovx)
#define FYc 256.0f   // H / (2*tanfovy)
#define P2MIN -7.9943534368588578f   // -log2(255)

#if __has_builtin(__builtin_amdgcn_exp2f)
#define EXP2F(x) __builtin_amdgcn_exp2f(x)
#else
#define EXP2F(x) exp2f(x)
#endif

// ---------------------------------------------------------------------------
// Two-kernel structure; intermediates live in __device__ globals (statically
// allocated at module load — no dependence on the harness workspace, which
// may be absent for this problem).
//
// Kernel 1 (gs_prep, 2 blocks x 256): preprocess each gaussian ONCE (vs the
// original version's 256x redundant per-row preprocessing). Emits:
//   g_q0[g] = {mx, my, A2, B2}
//   g_q1[g] = {C2, lop, f16x2(colR,colG), f16x2(colB,tz)}
//   g_cw[g] = {amarg, cmarg, qmax, tz}   (conservative-cull data + sort key)
// plus the radii output.
//
// Record math (log2 domain): p2 = A2*dx^2 + C2*dy^2 + B2*dx*dy + lop
//   alpha = min(0.99, exp2(p2)); valid <=> p2 <= lop && p2 >= -log2(255)
// Cull form: Q = a*dx^2 + b*dx*dy + c*dy^2 (PD), contribution needs Q <= qmax.
//   min over dx of Q = cmarg*dy^2 ; min over dy of Q = amarg*dx^2.
//
// Kernel 2 (gs_tile, 256 blocks x 256): one block per 16x16 pixel tile.
// Loads the 512 records (24 KB, L2-broadcast), 2-D conservative marginal
// cull (bit-exact-safe: only discards gaussians that cannot pass the
// reference's validity test anywhere in the tile), order-preserving ballot
// compaction, stable rank-sort by (tz, original index) matching jnp.argsort,
// then per-pixel front-to-back blend over the n sorted records via
// wave-uniform LDS broadcasts, with a wave-uniform early exit once
// transmittance < 1e-4 (residual error <= 1e-4, far under the tolerance).
// ---------------------------------------------------------------------------

__device__ __align__(16) float4 g_q0[NG];
__device__ __align__(16) float4 g_q1[NG];
__device__ __align__(16) float4 g_cw[NG];

__global__ __launch_bounds__(256) void gs_prep(
    const float* __restrict__ means,
    const float* __restrict__ opac,
    const float* __restrict__ cols,
    const float* __restrict__ scales,
    const float* __restrict__ rots,
    const float* __restrict__ Vm,
    const float* __restrict__ Pm,
    float* __restrict__ out)
{
    int g = blockIdx.x * 256 + threadIdx.x;   // grid(2) -> g in [0, 512)

    float qr = rots[g*4+0], qx = rots[g*4+1], qy = rots[g*4+2], qz = rots[g*4+3];
    float inv = rsqrtf(qr*qr + qx*qx + qy*qy + qz*qz);
    qr *= inv; qx *= inv; qy *= inv; qz *= inv;
    float R00 = 1.f - 2.f*(qy*qy + qz*qz);
    float R01 = 2.f*(qx*qy - qr*qz);
    float R02 = 2.f*(qx*qz + qr*qy);
    float R10 = 2.f*(qx*qy + qr*qz);
    float R11 = 1.f - 2.f*(qx*qx + qz*qz);
    float R12 = 2.f*(qy*qz - qr*qx);
    float R20 = 2.f*(qx*qz - qr*qy);
    float R21 = 2.f*(qy*qz + qr*qx);
    float R22 = 1.f - 2.f*(qx*qx + qy*qy);

    float s0 = scales[g*3+0], s1 = scales[g*3+1], s2 = scales[g*3+2];
    float M00=R00*s0, M01=R01*s1, M02=R02*s2;
    float M10=R10*s0, M11=R11*s1, M12=R12*s2;
    float M20=R20*s0, M21=R21*s1, M22=R22*s2;

    float S00 = M00*M00 + M01*M01 + M02*M02;
    float S01 = M00*M10 + M01*M11 + M02*M12;
    float S02 = M00*M20 + M01*M21 + M02*M22;
    float S11 = M10*M10 + M11*M11 + M12*M12;
    float S12 = M10*M20 + M11*M21 + M12*M22;
    float S22 = M20*M20 + M21*M21 + M22*M22;

    float px = means[g*3+0], py = means[g*3+1], pz = means[g*3+2];
    float t0 = px*Vm[0] + py*Vm[4] + pz*Vm[8]  + Vm[12];
    float t1 = px*Vm[1] + py*Vm[5] + pz*Vm[9]  + Vm[13];
    float tz = px*Vm[2] + py*Vm[6] + pz*Vm[10] + Vm[14];
    float tzc = fmaxf(tz, 1e-4f);
    const float limx = 1.3f*0.5f, limy = 1.3f*0.5f;
    float txc = fminf(fmaxf(t0 / tzc, -limx), limx) * tzc;
    float tyc = fminf(fmaxf(t1 / tzc, -limy), limy) * tzc;

    float J00 = FXc / tzc;
    float J02 = -FXc * txc / (tzc * tzc);
    float J11 = FYc / tzc;
    float J12 = -FYc * tyc / (tzc * tzc);

    float Ta0 = J00*Vm[0] + J02*Vm[2];
    float Ta1 = J00*Vm[4] + J02*Vm[6];
    float Ta2 = J00*Vm[8] + J02*Vm[10];
    float Tb0 = J11*Vm[1] + J12*Vm[2];
    float Tb1 = J11*Vm[5] + J12*Vm[6];
    float Tb2 = J11*Vm[9] + J12*Vm[10];

    float u0 = Ta0*S00 + Ta1*S01 + Ta2*S02;
    float u1 = Ta0*S01 + Ta1*S11 + Ta2*S12;
    float u2 = Ta0*S02 + Ta1*S12 + Ta2*S22;
    float v0 = Tb0*S00 + Tb1*S01 + Tb2*S02;
    float v1 = Tb0*S01 + Tb1*S11 + Tb2*S12;
    float v2 = Tb0*S02 + Tb1*S12 + Tb2*S22;
    float c00 = u0*Ta0 + u1*Ta1 + u2*Ta2 + 0.3f;
    float c01 = u0*Tb0 + u1*Tb1 + u2*Tb2;
    float c11 = v0*Tb0 + v1*Tb1 + v2*Tb2 + 0.3f;

    float det = c00*c11 - c01*c01;
    float det_inv = 1.f / ((det != 0.f) ? det : 1.f);
    float Aa =  c11 * det_inv;
    float Bb = -c01 * det_inv;
    float Cc =  c00 * det_inv;

    float mid = 0.5f*(c00 + c11);
    float lam = mid + sqrtf(fmaxf(mid*mid - det, 0.1f));
    bool vis = (det > 0.f) && (tz > 0.2f);
    float radf = vis ? ceilf(3.f*sqrtf(lam)) : 0.f;

    float h0 = px*Pm[0] + py*Pm[4] + pz*Pm[8]  + Pm[12];
    float h1 = px*Pm[1] + py*Pm[5] + pz*Pm[9]  + Pm[13];
    float h3 = px*Pm[3] + py*Pm[7] + pz*Pm[11] + Pm[15];
    float pw = 1.f / (h3 + 1e-7f);
    float mx = ((h0*pw + 1.f)*WI - 1.f)*0.5f;
    float my = ((h1*pw + 1.f)*HI - 1.f)*0.5f;

    float opv = vis ? opac[g] : 0.f;

    const float L2E = 1.4426950408889634f;
    float A2 = -0.5f*L2E*Aa;
    float B2 = -L2E*Bb;
    float C2 = -0.5f*L2E*Cc;
    float lop = (opv > 0.f) ? log2f(opv) : -3.0e38f;

    // conservative cull data: Q = a*dx^2 + b*dx*dy + c*dy^2 <= qmax required.
    float a  = 0.5f*L2E*Aa;
    float c  = 0.5f*L2E*Cc;
    float bq = L2E*Bb;
    float qmax  = (vis && opv > 0.f) ? (lop + 7.9943534368588578f) : -1.0f;
    float amarg = a - bq*bq/(4.f*c);   // min over dy of Q = amarg*dx^2
    float cmarg = c - bq*bq/(4.f*a);   // min over dx of Q = cmarg*dy^2

    out[5*WI*HI + g] = radf;

    union { __half2 h; float f; } prg, pbt;
    prg.h = __halves2half2(__float2half_rn(cols[g*3+0]), __float2half_rn(cols[g*3+1]));
    pbt.h = __halves2half2(__float2half_rn(cols[g*3+2]), __float2half_rn(tz));

    g_q0[g] = make_float4(mx, my, A2, B2);
    g_q1[g] = make_float4(C2, lop, prg.f, pbt.f);
    g_cw[g] = make_float4(amarg, cmarg, qmax, tz);
}

__global__ __launch_bounds__(256) void gs_tile(
    const float* __restrict__ bg,
    float* __restrict__ out)
{
    __shared__ __align__(16) float4 us[NG*2];   // compacted survivors, index order
    __shared__ __align__(16) float4 cs[NG*2];   // depth-sorted
    __shared__ float skey[NG];                  // survivor tz keys
    __shared__ int wtot[4];

    int tx   = threadIdx.x;
    int lane = tx & 63;
    int wv   = tx >> 6;
    int b    = blockIdx.x;
    int x0   = (b & 15) << 4;
    int y0   = (b >> 4) << 4;
    float fx0 = (float)x0, fx1 = (float)(x0 + 15);
    float fy0 = (float)y0, fy1 = (float)(y0 + 15);

    // ---- load 2 records/thread, 2-D conservative cull ----
    float4 a0 = g_q0[2*tx],   a1 = g_q0[2*tx+1];
    float4 b0 = g_q1[2*tx],   b1 = g_q1[2*tx+1];
    float4 c0 = g_cw[2*tx],   c1 = g_cw[2*tx+1];

    // distance from mean to tile box, with 0.0625 px conservative slack
    float dxm0 = fmaxf(0.f, fmaxf(fx0 - a0.x, a0.x - fx1) - 0.0625f);
    float dym0 = fmaxf(0.f, fmaxf(fy0 - a0.y, a0.y - fy1) - 0.0625f);
    float dxm1 = fmaxf(0.f, fmaxf(fx0 - a1.x, a1.x - fx1) - 0.0625f);
    float dym1 = fmaxf(0.f, fmaxf(fy0 - a1.y, a1.y - fy1) - 0.0625f);
    // qmax < 0 (invisible/zero-op) fails both tests; NaN coords fail too.
    bool f0 = (c0.x*dxm0*dxm0 <= c0.z) && (c0.y*dym0*dym0 <= c0.z);
    bool f1 = (c1.x*dxm1*dxm1 <= c1.z) && (c1.y*dym1*dym1 <= c1.z);

    // ---- order-preserving ballot compaction into LDS ----
    unsigned long long m0 = __ballot(f0);
    unsigned long long m1 = __ballot(f1);
    unsigned long long lt = (1ULL << lane) - 1ULL;
    int pre = __popcll(m0 & lt) + __popcll(m1 & lt);
    if (lane == 0) wtot[wv] = __popcll(m0) + __popcll(m1);
    __syncthreads();

    int base = 0, n = 0;
    #pragma unroll
    for (int w2 = 0; w2 < 4; ++w2) {
        int t = wtot[w2];
        base += (w2 < wv) ? t : 0;
        n += t;
    }

    int p0 = base + pre;
    if (f0) {
        us[p0*2+0] = a0;
        us[p0*2+1] = b0;
        skey[p0]   = c0.w;
    }
    if (f1) {
        int p1 = p0 + (f0 ? 1 : 0);
        us[p1*2+0] = a1;
        us[p1*2+1] = b1;
        skey[p1]   = c1.w;
    }
    __syncthreads();

    // ---- rank-sort n survivors by tz (stable via slot = original order) ----
    for (int s = tx; s < n; s += 256) {
        float k = skey[s];
        int rank = 0;
        for (int j = 0; j < n; ++j) {
            float o = skey[j];
            rank += (o < k) || ((o == k) && (j < s));
        }
        cs[2*rank+0] = us[2*s+0];
        cs[2*rank+1] = us[2*s+1];
    }
    __syncthreads();

    // ---- per-pixel front-to-back blend over sorted survivors ----
    float pxf = (float)(x0 + (tx & 15));
    float pyf = (float)(y0 + (tx >> 4));
    float T = 1.f, cr = 0.f, cg = 0.f, cb = 0.f, dp = 0.f;
    for (int j = 0; j < n; ++j) {
        float4 a = cs[2*j+0];    // mx, my, A2, B2   (wave-uniform broadcast)
        float4 q = cs[2*j+1];    // C2, lop, rg16, bt16
        float dx = a.x - pxf;
        float dy = a.y - pyf;
        float p2 = fmaf(fmaf(a.z, dx, a.w*dy), dx, fmaf(q.x*dy, dy, q.y));
        float al = fminf(0.99f, EXP2F(p2));
        al = ((p2 <= q.y) && (p2 >= P2MIN)) ? al : 0.f;
        float w = al * T;
        union { float f; __half2 h; } urg, ubt;
        urg.f = q.z; ubt.f = q.w;
        cr = fmaf(w, __low2float(urg.h),  cr);
        cg = fmaf(w, __high2float(urg.h), cg);
        cb = fmaf(w, __low2float(ubt.h),  cb);
        dp = fmaf(w, __high2float(ubt.h), dp);
        T -= w;
        if (__all(T < 1e-4f)) break;   // remaining contribution <= 1e-4
    }

    const int HW = WI * HI;
    int p = (y0 + (tx >> 4)) * WI + x0 + (tx & 15);
    out[p]        = cr + T * bg[0];
    out[HW+p]     = cg + T * bg[1];
    out[2*HW+p]   = cb + T * bg[2];
    out[3*HW+p]   = dp;
    out[4*HW+p]   = T;
}

extern "C" void kernel_launch(void* const* d_in, const int* in_sizes, int n_in,
                              void* d_out, int out_size, void* d_ws, size_t ws_size,
                              hipStream_t stream)
{
    const float* means  = (const float*)d_in[0];
    const float* opac   = (const float*)d_in[1];
    const float* cols   = (const float*)d_in[2];
    const float* scales = (const float*)d_in[3];
    const float* rots   = (const float*)d_in[4];
    const float* bg     = (const float*)d_in[5];
    const float* Vm     = (const float*)d_in[6];
    const float* Pm     = (const float*)d_in[7];

    float* out = (float*)d_out;

    hipLaunchKernelGGL(gs_prep, dim3(2), dim3(256), 0, stream,
                       means, opac, cols, scales, rots, Vm, Pm, out);
    hipLaunchKernelGGL(gs_tile, dim3(256), dim3(256), 0, stream,
                       bg, out);
}